// Round 8
// baseline (655.360 us; speedup 1.0000x reference)
//
#include <hip/hip_runtime.h>

#define NBLOCKS 8192
#define NTHREADS 256
#define GROUPS 4
// 8192 blocks * 256 threads = 2^21 threads * 4 float4 groups = 2^25 elements.
// 8 independent NT loads in flight per thread (R5-proven structure).

typedef float fvec4 __attribute__((ext_vector_type(4)));
typedef int   ivec4 __attribute__((ext_vector_type(4)));

__device__ __forceinline__ fvec4 ntloadf(const fvec4* p) {
    return __builtin_nontemporal_load(p);
}
__device__ __forceinline__ ivec4 ntloadi(const ivec4* p) {
    return __builtin_nontemporal_load(p);
}

__global__ __launch_bounds__(NTHREADS) void wmse_kernel(
    const fvec4* __restrict__ pred4,
    const ivec4* __restrict__ lab4,
    const float* __restrict__ weights,
    double* __restrict__ partials,
    unsigned* __restrict__ counter,   // zeroed by memset node each launch
    float* __restrict__ out,
    int n4, double inv_n)
{
    __shared__ float w[16];
    if (threadIdx.x < 10) w[threadIdx.x] = weights[threadIdx.x];
    __syncthreads();

    const int stride = NBLOCKS * NTHREADS;
    const int t = blockIdx.x * NTHREADS + threadIdx.x;

    double acc = 0.0;

    if (n4 == stride * GROUPS) {
        fvec4 p0 = ntloadf(pred4 + t);
        fvec4 p1 = ntloadf(pred4 + t + stride);
        fvec4 p2 = ntloadf(pred4 + t + 2 * stride);
        fvec4 p3 = ntloadf(pred4 + t + 3 * stride);
        ivec4 l0 = ntloadi(lab4 + t);
        ivec4 l1 = ntloadi(lab4 + t + stride);
        ivec4 l2 = ntloadi(lab4 + t + 2 * stride);
        ivec4 l3 = ntloadi(lab4 + t + 3 * stride);

        float s0, s1, s2, s3;
        {
            float d0 = p0.x - (float)l0.x, d1 = p0.y - (float)l0.y;
            float d2 = p0.z - (float)l0.z, d3 = p0.w - (float)l0.w;
            s0 = w[l0.x]*d0*d0 + w[l0.y]*d1*d1 + w[l0.z]*d2*d2 + w[l0.w]*d3*d3;
        }
        {
            float d0 = p1.x - (float)l1.x, d1 = p1.y - (float)l1.y;
            float d2 = p1.z - (float)l1.z, d3 = p1.w - (float)l1.w;
            s1 = w[l1.x]*d0*d0 + w[l1.y]*d1*d1 + w[l1.z]*d2*d2 + w[l1.w]*d3*d3;
        }
        {
            float d0 = p2.x - (float)l2.x, d1 = p2.y - (float)l2.y;
            float d2 = p2.z - (float)l2.z, d3 = p2.w - (float)l2.w;
            s2 = w[l2.x]*d0*d0 + w[l2.y]*d1*d1 + w[l2.z]*d2*d2 + w[l2.w]*d3*d3;
        }
        {
            float d0 = p3.x - (float)l3.x, d1 = p3.y - (float)l3.y;
            float d2 = p3.z - (float)l3.z, d3 = p3.w - (float)l3.w;
            s3 = w[l3.x]*d0*d0 + w[l3.y]*d1*d1 + w[l3.z]*d2*d2 + w[l3.w]*d3*d3;
        }
        acc = (double)((s0 + s1) + (s2 + s3));
    } else {
        for (int i = t; i < n4; i += stride) {
            fvec4 p = pred4[i];
            ivec4 l = lab4[i];
            float d0 = p.x - (float)l.x, d1 = p.y - (float)l.y;
            float d2 = p.z - (float)l.z, d3 = p.w - (float)l.w;
            acc += (double)(w[l.x]*d0*d0 + w[l.y]*d1*d1
                          + w[l.z]*d2*d2 + w[l.w]*d3*d3);
        }
    }

    // 64-lane wave shuffle reduction (f64)
    for (int off = 32; off > 0; off >>= 1)
        acc += __shfl_down(acc, off, 64);

    __shared__ double wave_sums[NTHREADS / 64];
    __shared__ int is_last;
    int lane = threadIdx.x & 63;
    int wid  = threadIdx.x >> 6;
    if (lane == 0) wave_sums[wid] = acc;
    __syncthreads();

    if (threadIdx.x == 0) {
        double tsum = 0.0;
        #pragma unroll
        for (int k = 0; k < NTHREADS / 64; ++k) tsum += wave_sums[k];
        // publish partial (agent-scope), then arrive at counter with release
        __hip_atomic_store(&partials[blockIdx.x], tsum,
                           __ATOMIC_RELAXED, __HIP_MEMORY_SCOPE_AGENT);
        unsigned old = __hip_atomic_fetch_add(counter, 1u,
                           __ATOMIC_ACQ_REL, __HIP_MEMORY_SCOPE_AGENT);
        is_last = (old == NBLOCKS - 1) ? 1 : 0;
    }
    __syncthreads();

    if (is_last) {
        // last-arriving block reduces all 8192 partials (64 KB)
        double a = 0.0;
        for (int i = threadIdx.x; i < NBLOCKS; i += NTHREADS)
            a += __hip_atomic_load(&partials[i],
                                   __ATOMIC_RELAXED, __HIP_MEMORY_SCOPE_AGENT);
        for (int off = 32; off > 0; off >>= 1)
            a += __shfl_down(a, off, 64);
        __shared__ double fin[NTHREADS / 64];
        if (lane == 0) fin[wid] = a;
        __syncthreads();
        if (threadIdx.x == 0) {
            double tot = 0.0;
            #pragma unroll
            for (int k = 0; k < NTHREADS / 64; ++k) tot += fin[k];
            out[0] = (float)(tot * inv_n);
        }
    }
}

extern "C" void kernel_launch(void* const* d_in, const int* in_sizes, int n_in,
                              void* d_out, int out_size, void* d_ws, size_t ws_size,
                              hipStream_t stream) {
    const float* pred    = (const float*)d_in[0];
    const int*   labels  = (const int*)d_in[1];
    const float* weights = (const float*)d_in[2];
    float* out = (float*)d_out;

    int n  = in_sizes[0];          // 33,554,432 = 2^25
    int n4 = n >> 2;

    double*   partials = (double*)d_ws;                       // 64 KB
    unsigned* counter  = (unsigned*)((char*)d_ws + NBLOCKS * sizeof(double));

    // counter is poisoned to 0xAA each replay — zero just these 4 bytes
    hipMemsetAsync(counter, 0, sizeof(unsigned), stream);

    wmse_kernel<<<NBLOCKS, NTHREADS, 0, stream>>>(
        (const fvec4*)pred, (const ivec4*)labels, weights,
        partials, counter, out, n4, 1.0 / (double)n);
}

// Round 9
// 254.579 us; speedup vs baseline: 2.5743x; 2.5743x over previous
//
#include <hip/hip_runtime.h>

#define NBLOCKS 8192
#define NTHREADS 256
#define GROUPS 4
// 8192 blocks * 256 threads = 2^21 threads * 4 float4 groups = 2^25 elements.
// R5-proven structure: NT (L1-bypass) streaming loads, partials to d_ws,
// separate tiny final kernel. NO single-address atomics (R7/R8: 7-55 ns each,
// 8192 serialized = 60-450 us tail).

typedef float fvec4 __attribute__((ext_vector_type(4)));
typedef int   ivec4 __attribute__((ext_vector_type(4)));
typedef double dvec2 __attribute__((ext_vector_type(2)));

__device__ __forceinline__ fvec4 ntloadf(const fvec4* p) {
    return __builtin_nontemporal_load(p);
}
__device__ __forceinline__ ivec4 ntloadi(const ivec4* p) {
    return __builtin_nontemporal_load(p);
}

__global__ __launch_bounds__(NTHREADS) void wmse_kernel(
    const fvec4* __restrict__ pred4,
    const ivec4* __restrict__ lab4,
    const float* __restrict__ weights,
    double* __restrict__ partials,
    int n4)
{
    __shared__ float w[16];
    if (threadIdx.x < 10) w[threadIdx.x] = weights[threadIdx.x];
    __syncthreads();

    const int stride = NBLOCKS * NTHREADS;       // 2^21 float4 groups
    const int t = blockIdx.x * NTHREADS + threadIdx.x;

    double acc = 0.0;

    if (n4 == stride * GROUPS) {
        // ---- flat fast path: NT streaming loads ----
        fvec4 p0 = ntloadf(pred4 + t);
        fvec4 p1 = ntloadf(pred4 + t + stride);
        fvec4 p2 = ntloadf(pred4 + t + 2 * stride);
        fvec4 p3 = ntloadf(pred4 + t + 3 * stride);
        ivec4 l0 = ntloadi(lab4 + t);
        ivec4 l1 = ntloadi(lab4 + t + stride);
        ivec4 l2 = ntloadi(lab4 + t + 2 * stride);
        ivec4 l3 = ntloadi(lab4 + t + 3 * stride);

        float s0, s1, s2, s3;
        {
            float d0 = p0.x - (float)l0.x, d1 = p0.y - (float)l0.y;
            float d2 = p0.z - (float)l0.z, d3 = p0.w - (float)l0.w;
            s0 = w[l0.x]*d0*d0 + w[l0.y]*d1*d1 + w[l0.z]*d2*d2 + w[l0.w]*d3*d3;
        }
        {
            float d0 = p1.x - (float)l1.x, d1 = p1.y - (float)l1.y;
            float d2 = p1.z - (float)l1.z, d3 = p1.w - (float)l1.w;
            s1 = w[l1.x]*d0*d0 + w[l1.y]*d1*d1 + w[l1.z]*d2*d2 + w[l1.w]*d3*d3;
        }
        {
            float d0 = p2.x - (float)l2.x, d1 = p2.y - (float)l2.y;
            float d2 = p2.z - (float)l2.z, d3 = p2.w - (float)l2.w;
            s2 = w[l2.x]*d0*d0 + w[l2.y]*d1*d1 + w[l2.z]*d2*d2 + w[l2.w]*d3*d3;
        }
        {
            float d0 = p3.x - (float)l3.x, d1 = p3.y - (float)l3.y;
            float d2 = p3.z - (float)l3.z, d3 = p3.w - (float)l3.w;
            s3 = w[l3.x]*d0*d0 + w[l3.y]*d1*d1 + w[l3.z]*d2*d2 + w[l3.w]*d3*d3;
        }
        acc = (double)((s0 + s1) + (s2 + s3));
    } else {
        // generic fallback (not taken for N = 2^25)
        for (int i = t; i < n4; i += stride) {
            fvec4 p = pred4[i];
            ivec4 l = lab4[i];
            float d0 = p.x - (float)l.x, d1 = p.y - (float)l.y;
            float d2 = p.z - (float)l.z, d3 = p.w - (float)l.w;
            acc += (double)(w[l.x]*d0*d0 + w[l.y]*d1*d1
                          + w[l.z]*d2*d2 + w[l.w]*d3*d3);
        }
    }

    // 64-lane wave shuffle reduction (f64)
    for (int off = 32; off > 0; off >>= 1)
        acc += __shfl_down(acc, off, 64);

    __shared__ double wave_sums[NTHREADS / 64];
    int lane = threadIdx.x & 63;
    int wid  = threadIdx.x >> 6;
    if (lane == 0) wave_sums[wid] = acc;
    __syncthreads();

    if (threadIdx.x == 0) {
        double tsum = 0.0;
        #pragma unroll
        for (int k = 0; k < NTHREADS / 64; ++k) tsum += wave_sums[k];
        partials[blockIdx.x] = tsum;
    }
}

#define FTHREADS 1024

__global__ __launch_bounds__(FTHREADS) void wmse_final_kernel(
    const dvec2* __restrict__ partials2,   // NBLOCKS/2 double2s
    float* __restrict__ out,
    double inv_n)
{
    // NBLOCKS/2 = 4096 double2; 1024 threads -> 4 vector loads each
    double acc = 0.0;
    #pragma unroll
    for (int k = 0; k < NBLOCKS / 2 / FTHREADS; ++k) {
        dvec2 v = partials2[threadIdx.x + k * FTHREADS];
        acc += v.x + v.y;
    }

    for (int off = 32; off > 0; off >>= 1)
        acc += __shfl_down(acc, off, 64);

    __shared__ double wave_sums[FTHREADS / 64];
    int lane = threadIdx.x & 63;
    int wid  = threadIdx.x >> 6;
    if (lane == 0) wave_sums[wid] = acc;
    __syncthreads();

    if (threadIdx.x == 0) {
        double t = 0.0;
        #pragma unroll
        for (int k = 0; k < FTHREADS / 64; ++k) t += wave_sums[k];
        out[0] = (float)(t * inv_n);
    }
}

extern "C" void kernel_launch(void* const* d_in, const int* in_sizes, int n_in,
                              void* d_out, int out_size, void* d_ws, size_t ws_size,
                              hipStream_t stream) {
    const float* pred    = (const float*)d_in[0];
    const int*   labels  = (const int*)d_in[1];
    const float* weights = (const float*)d_in[2];
    float* out = (float*)d_out;

    int n  = in_sizes[0];          // 33,554,432 = 2^25
    int n4 = n >> 2;

    double* partials = (double*)d_ws;   // 8192 doubles = 64 KB

    wmse_kernel<<<NBLOCKS, NTHREADS, 0, stream>>>(
        (const fvec4*)pred, (const ivec4*)labels, weights, partials, n4);

    wmse_final_kernel<<<1, FTHREADS, 0, stream>>>(
        (const dvec2*)partials, out, 1.0 / (double)n);
}